// Round 1
// 379.324 us; speedup vs baseline: 1.1353x; 1.1353x over previous
//
#include <hip/hip_runtime.h>

typedef unsigned short u16;
typedef __attribute__((ext_vector_type(8))) short bf8_t;   // 8 bf16 (4 VGPR) MFMA A/B frag
typedef __attribute__((ext_vector_type(4))) float f4_t;    // MFMA C/D frag (16x16)
typedef __attribute__((ext_vector_type(16))) float fx16;   // MFMA C/D frag (32x32)

__device__ __forceinline__ float bf2f(u16 v) {
    union { unsigned u; float f; } c; c.u = ((unsigned)v) << 16; return c.f;
}
__device__ __forceinline__ u16 f2bf(float f) {  // RNE f32 -> bf16
    union { float f; unsigned u; } c; c.f = f;
    unsigned r = 0x7FFFu + ((c.u >> 16) & 1u);
    return (u16)((c.u + r) >> 16);
}

#define B_   4
#define N_   2048
#define INC  256
#define H_   8
#define ROWS 8192

// canonical (bf16) segment offsets within cvt, u16 units. Weights stored TRANSPOSED: Bt[n][k].
#define SEG_X     0
#define SEG_LN1G  2097152
#define SEG_LN1B  2097408
#define SEG_WQKV  2097664
#define SEG_BQKV  2753024
#define SEG_WM    2755584
#define SEG_BM    3279872
#define SEG_LN2G  3280128
#define SEG_LN2B  3280384
#define SEG_W1    3280640
#define SEG_B1    3542784
#define SEG_W2    3543808
#define SEG_B2    3805952
#define SEG_TOT   3806208

// ---------------- dtype sniffer ----------------
__global__ __launch_bounds__(256) void sniff_k(const u16* __restrict__ x, int* __restrict__ flag) {
    __shared__ int s;
    int t = threadIdx.x;
    if (t == 0) s = 0;
    __syncthreads();
    int bad = 0;
    for (int i = t; i < 8192; i += 256) {
        float v = bf2f(x[i]);
        if (!(fabsf(v) < 1e10f)) bad = 1;
    }
    if (bad) atomicOr(&s, 1);
    __syncthreads();
    if (t == 0) *flag = s;   // 1 => inputs fp32, 0 => bf16
}

// ---------------- canonicalize inputs to bf16; weights transposed ----------------
__global__ __launch_bounds__(256) void conv_k(
    const void* p0, const void* p1, const void* p2, const void* p3, const void* p4,
    const void* p5, const void* p6, const void* p7, const void* p8, const void* p9,
    const void* p10, const void* p11, const void* p12,
    const int* __restrict__ flag, u16* __restrict__ dst)
{
    int i = blockIdx.x * 256 + threadIdx.x;
    if (i >= SEG_TOT) return;
    const void* p; int j;
    if      (i < SEG_LN1G) { p = p0;  j = i; }
    else if (i < SEG_LN1B) { p = p1;  j = i - SEG_LN1G; }
    else if (i < SEG_WQKV) { p = p2;  j = i - SEG_LN1B; }
    else if (i < SEG_BQKV) { p = p3;  int ii = i - SEG_WQKV;          // WqkvT[n][k]: n<2560,k<256
                             int n = ii >> 8, k = ii & 255; j = k * 2560 + n; }
    else if (i < SEG_WM)   { p = p4;  j = i - SEG_BQKV; }
    else if (i < SEG_BM)   { p = p5;  int ii = i - SEG_WM;            // WmT[n][k]: n<256,k<2048
                             int n = ii >> 11, k = ii & 2047; j = k * 256 + n; }
    else if (i < SEG_LN2G) { p = p6;  j = i - SEG_BM; }
    else if (i < SEG_LN2B) { p = p7;  j = i - SEG_LN2G; }
    else if (i < SEG_W1)   { p = p8;  j = i - SEG_LN2B; }
    else if (i < SEG_B1)   { p = p9;  int ii = i - SEG_W1;            // W1T[n][k]: n<1024,k<256
                             int n = ii >> 8, k = ii & 255; j = k * 1024 + n; }
    else if (i < SEG_W2)   { p = p10; j = i - SEG_B1; }
    else if (i < SEG_B2)   { p = p11; int ii = i - SEG_W2;            // W2T[n][k]: n<256,k<1024
                             int n = ii >> 10, k = ii & 1023; j = k * 256 + n; }
    else                   { p = p12; j = i - SEG_B2; }
    dst[i] = (*flag) ? f2bf(((const float*)p)[j]) : ((const u16*)p)[j];
}

// ---------------- LayerNorm, one wave per row (no barriers), 4 rows/block ----------------
template<bool BF16IN>
__global__ __launch_bounds__(256) void ln_k(const void* __restrict__ xp,
        const u16* __restrict__ g, const u16* __restrict__ b, u16* __restrict__ y)
{
    int row  = blockIdx.x * 4 + (threadIdx.x >> 6);
    int lane = threadIdx.x & 63;
    int c0   = lane * 4;
    float v[4];
    if (BF16IN) {
        ushort4 u = *(const ushort4*)((const u16*)xp + (size_t)row * INC + c0);
        v[0] = bf2f(u.x); v[1] = bf2f(u.y); v[2] = bf2f(u.z); v[3] = bf2f(u.w);
    } else {
        float4 f = *(const float4*)((const float*)xp + (size_t)row * INC + c0);
        v[0] = f.x; v[1] = f.y; v[2] = f.z; v[3] = f.w;
    }
    float s = v[0] + v[1] + v[2] + v[3];
    float s2 = v[0]*v[0] + v[1]*v[1] + v[2]*v[2] + v[3]*v[3];
    #pragma unroll
    for (int d = 1; d < 64; d <<= 1) {
        s  += __shfl_xor(s,  d, 64);
        s2 += __shfl_xor(s2, d, 64);
    }
    float mean = s * (1.0f / INC);
    float var  = s2 * (1.0f / INC) - mean * mean;
    float inv  = rsqrtf(var + 1e-5f);
    ushort4 gv = *(const ushort4*)(g + c0);
    ushort4 bv = *(const ushort4*)(b + c0);
    ushort4 o;
    o.x = f2bf((v[0] - mean) * inv * bf2f(gv.x) + bf2f(bv.x));
    o.y = f2bf((v[1] - mean) * inv * bf2f(gv.y) + bf2f(bv.y));
    o.z = f2bf((v[2] - mean) * inv * bf2f(gv.z) + bf2f(bv.z));
    o.w = f2bf((v[3] - mean) * inv * bf2f(gv.w) + bf2f(bv.w));
    *(ushort4*)(y + (size_t)row * INC + c0) = o;
}

// ---------------- per-head max key L2-norm (K tiled layout [bh][kb][cb][key32][ch16]) ------
__global__ __launch_bounds__(256) void maxk_k(const u16* __restrict__ kh, float* __restrict__ mk) {
    int bh = blockIdx.x, t = threadIdx.x;
    float mx = 0.f;
    for (int n = t; n < 2048; n += 256) {
        const u16* kr = kh + ((size_t)bh * 64 + (n >> 5)) * 1024 + (n & 31) * 16;
        float s = 0.f;
        #pragma unroll
        for (int cb = 0; cb < 2; ++cb)
            #pragma unroll
            for (int c4 = 0; c4 < 4; ++c4) {
                ushort4 v = *(const ushort4*)(kr + cb * 512 + c4 * 4);
                float f0 = bf2f(v.x), f1 = bf2f(v.y), f2 = bf2f(v.z), f3 = bf2f(v.w);
                s += f0 * f0 + f1 * f1 + f2 * f2 + f3 * f3;
            }
        mx = fmaxf(mx, s);
    }
    #pragma unroll
    for (int d = 1; d < 64; d <<= 1) mx = fmaxf(mx, __shfl_xor(mx, d, 64));
    __shared__ float red[4];
    if ((t & 63) == 0) red[t >> 6] = mx;
    __syncthreads();
    if (t == 0) mk[bh] = sqrtf(fmaxf(fmaxf(red[0], red[1]), fmaxf(red[2], red[3])));
}

enum { EP_QKV = 0, EP_MERGE = 1, EP_GELU = 2, EP_FFN2 = 3 };

// ---------------- big-tile GEMM (QKV / GELU): wave 64x64, block 256x64, 2:1 MFMA:load ----
template<int MODE>
__global__ __launch_bounds__(256) void gemm_big(
    const u16* __restrict__ A, const u16* __restrict__ Bt,
    const u16* __restrict__ bias, void* __restrict__ outp,
    u16* __restrict__ qh, u16* __restrict__ kh, u16* __restrict__ vh,
    int N, int K)
{
    const int t = threadIdx.x;
    const int w = t >> 6, lane = t & 63;
    const int l15 = lane & 15, quad = lane >> 4;
    const int col0 = blockIdx.x * 64;
    const int row0 = blockIdx.y * 256;
    const int mrow = row0 + w * 64;

    const u16* Ap = A  + (size_t)(mrow + l15) * K + quad * 8;
    const u16* Bp = Bt + (size_t)(col0 + l15) * K + quad * 8;

    f4_t acc[4][4];
    #pragma unroll
    for (int mi = 0; mi < 4; ++mi)
        #pragma unroll
        for (int ni = 0; ni < 4; ++ni)
            acc[mi][ni] = (f4_t){0.f, 0.f, 0.f, 0.f};

    for (int k0 = 0; k0 < K; k0 += 32) {
        bf8_t a[4], bb[4];
        #pragma unroll
        for (int mi = 0; mi < 4; ++mi)
            a[mi] = *(const bf8_t*)(Ap + (size_t)mi * 16 * K + k0);
        #pragma unroll
        for (int ni = 0; ni < 4; ++ni)
            bb[ni] = *(const bf8_t*)(Bp + (size_t)ni * 16 * K + k0);
        #pragma unroll
        for (int ni = 0; ni < 4; ++ni)
            #pragma unroll
            for (int mi = 0; mi < 4; ++mi)
                acc[mi][ni] = __builtin_amdgcn_mfma_f32_16x16x32_bf16(
                    a[mi], bb[ni], acc[mi][ni], 0, 0, 0);
    }

    if (MODE == EP_QKV) {
        if (col0 >= 512) {
            // V: transpose 256 tokens x 64 chans through LDS -> vh tiled [bh][tok/16][vc256][tok%16]
            __shared__ u16 Ts[64][268];
            #pragma unroll
            for (int mi = 0; mi < 4; ++mi)
                #pragma unroll
                for (int ni = 0; ni < 4; ++ni) {
                    float bz = bf2f(bias[col0 + ni * 16 + l15]);
                    #pragma unroll
                    for (int r = 0; r < 4; ++r)
                        Ts[ni * 16 + l15][w * 64 + mi * 16 + quad * 4 + r] =
                            f2bf(acc[mi][ni][r] + bz);
                }
            __syncthreads();
            int vcg = col0 - 512;
            int hh  = vcg >> 8;
            int bb2 = row0 >> 11, nb = row0 & 2047;
            int bhh = bb2 * 8 + hh;
            int tok4 = t & 3, cl = (t >> 2) & 63;
            int vc = (vcg & 255) + cl;
            // each kb-iteration: 256 threads store one fully-contiguous 2KB tile
            #pragma unroll
            for (int kb = 0; kb < 16; ++kb) {
                u16* dp = vh + (((size_t)bhh * 128 + ((nb >> 4) + kb)) * 256 + vc) * 16 + tok4 * 4;
                *(ushort4*)dp = *(const ushort4*)&Ts[cl][kb * 16 + tok4 * 4];
            }
        } else {
            #pragma unroll
            for (int mi = 0; mi < 4; ++mi)
                #pragma unroll
                for (int r = 0; r < 4; ++r) {
                    int rg = mrow + mi * 16 + quad * 4 + r;
                    int bb2 = rg >> 11, n = rg & 2047;
                    #pragma unroll
                    for (int ni = 0; ni < 4; ++ni) {
                        int col = col0 + ni * 16 + l15;
                        float v = acc[mi][ni][r] + bf2f(bias[col]);
                        if (col < 256)
                            qh[(((size_t)(bb2 * 8 + (col >> 5))) * 2048 + n) * 32 + (col & 31)] = f2bf(v);
                        else {
                            // K tiled: [bh][n/32][ch/16][n%32][ch%16]
                            int c2 = col - 256;
                            int hd = c2 >> 5, ch = c2 & 31;
                            kh[(((size_t)(bb2 * 8 + hd) * 64 + (n >> 5)) * 2 + (ch >> 4)) * 512
                               + (n & 31) * 16 + (ch & 15)] = f2bf(v);
                        }
                    }
                }
        }
    } else {   // EP_GELU: exact gelu -> bf16 hidden
        float bz[4];
        #pragma unroll
        for (int ni = 0; ni < 4; ++ni) bz[ni] = bf2f(bias[col0 + ni * 16 + l15]);
        #pragma unroll
        for (int mi = 0; mi < 4; ++mi)
            #pragma unroll
            for (int r = 0; r < 4; ++r) {
                int rg = mrow + mi * 16 + quad * 4 + r;
                size_t base = (size_t)rg * N + col0 + l15;
                #pragma unroll
                for (int ni = 0; ni < 4; ++ni) {
                    float v = acc[mi][ni][r] + bz[ni];
                    v = 0.5f * v * (1.0f + erff(v * 0.70710678118654752f));
                    ((u16*)outp)[base + ni * 16] = f2bf(v);
                }
            }
    }
}

// ---------------- MFMA GEMM (MERGE / FFN2): block 128x64 ----------------
template<int MODE>
__global__ __launch_bounds__(256) void gemm_mfma(
    const u16* __restrict__ A, const u16* __restrict__ Bt,
    const u16* __restrict__ bias, const void* __restrict__ res,
    void* __restrict__ outp, int N, int K)
{
    const int t = threadIdx.x;
    const int w = t >> 6, lane = t & 63;
    const int l15 = lane & 15, quad = lane >> 4;
    const int col0 = blockIdx.x * 64;
    const int row0 = blockIdx.y * 128;
    const int mrow = row0 + w * 32;

    const u16* Ap = A  + (size_t)(mrow + l15) * K + quad * 8;
    const u16* Bp = Bt + (size_t)(col0 + l15) * K + quad * 8;

    f4_t acc[2][4];
    #pragma unroll
    for (int mi = 0; mi < 2; ++mi)
        #pragma unroll
        for (int ni = 0; ni < 4; ++ni)
            acc[mi][ni] = (f4_t){0.f, 0.f, 0.f, 0.f};

    for (int k0 = 0; k0 < K; k0 += 64) {
        bf8_t a[2][2], bb[4][2];
        #pragma unroll
        for (int kc = 0; kc < 2; ++kc) {
            #pragma unroll
            for (int mi = 0; mi < 2; ++mi)
                a[mi][kc] = *(const bf8_t*)(Ap + (size_t)mi * 16 * K + k0 + kc * 32);
            #pragma unroll
            for (int ni = 0; ni < 4; ++ni)
                bb[ni][kc] = *(const bf8_t*)(Bp + (size_t)ni * 16 * K + k0 + kc * 32);
        }
        #pragma unroll
        for (int kc = 0; kc < 2; ++kc)
            #pragma unroll
            for (int ni = 0; ni < 4; ++ni)
                #pragma unroll
                for (int mi = 0; mi < 2; ++mi)
                    acc[mi][ni] = __builtin_amdgcn_mfma_f32_16x16x32_bf16(
                        a[mi][kc], bb[ni][kc], acc[mi][ni], 0, 0, 0);
    }

    float bz[4];
    #pragma unroll
    for (int ni = 0; ni < 4; ++ni) bz[ni] = bf2f(bias[col0 + ni * 16 + l15]);
    #pragma unroll
    for (int mi = 0; mi < 2; ++mi)
        #pragma unroll
        for (int r = 0; r < 4; ++r) {
            int rg = mrow + mi * 16 + quad * 4 + r;
            size_t base = (size_t)rg * N + col0 + l15;
            if (MODE == EP_MERGE) {          // + bm + x (bf16) -> f32 x2
                const u16* R = (const u16*)res;
                #pragma unroll
                for (int ni = 0; ni < 4; ++ni)
                    ((float*)outp)[base + ni * 16] =
                        acc[mi][ni][r] + bz[ni] + bf2f(R[base + ni * 16]);
            } else {                          // EP_FFN2: + x2 (f32) -> fp32 d_out
                const float* R = (const float*)res;
                #pragma unroll
                for (int ni = 0; ni < 4; ++ni)
                    ((float*)outp)[base + ni * 16] =
                        acc[mi][ni][r] + bz[ni] + R[base + ni * 16];
            }
        }
}

// ---------------- MFMA flash attention, 32x32x16 form ----------------
// Per block: 64 queries, 4 waves. Per 128-key chunk:
//   QK:  wave w computes S^T tile (32 keys = w*32.. x 64 q) with 4 x mfma_32x32x16
//        (2 qtiles x 2 ch-halves), exp with norm-bound max, packs P -> LDS Pb (XOR-swizzled).
//   PV:  each wave computes all 64 q x its 64 vchans: 8 ksteps x {2 ds_read_b128 (P),
//        2 contiguous 2KB V loads (tiled layout), 4 x mfma_32x32x16} with setprio(1).
// NOTE: plain launch_bounds(256). Capping VGPR below the 64-reg accumulator spills (R12 lesson).
__global__ __launch_bounds__(256) void attn_k(
    const u16* __restrict__ qh, const u16* __restrict__ kh,
    const u16* __restrict__ vhT, const float* __restrict__ maxk,
    u16* __restrict__ ao)
{
    const int t = threadIdx.x;
    const int w = t >> 6, lane = t & 63;
    const int l31 = lane & 31, hi = lane >> 5;
    const int id = blockIdx.x;
    const int qt = (id >> 3) & 31;
    const int bh = (id >> 8) * 8 + (id & 7);   // id%8 = XCD affinity per (b,h)
    const int b  = bh >> 3, h = bh & 7;
    const int n0 = qt * 64;
    const float SCALE = 0.17677669529663687f;  // 1/sqrt(32)
    const int sw = (l31 & 7) << 4;             // LDS XOR swizzle (byte bits 4-6)

    __shared__ __align__(16) u16 Pb[2][64][128];  // [buf][q][key], stride 256B, XOR-swizzled
    __shared__ float lds_l[4][64];
    __shared__ float lds_t[64];

    // Q fragments: qf[m][ks] = Q[n0+m*32+l31][ks*16 + hi*8 .. +8]  (B operand of QK)
    bf8_t qf[2][2];
    #pragma unroll
    for (int m = 0; m < 2; ++m)
        #pragma unroll
        for (int ks = 0; ks < 2; ++ks)
            qf[m][ks] = *(const bf8_t*)(qh + ((size_t)bh * 2048 + n0 + m * 32 + l31) * 32
                                        + ks * 16 + hi * 8);

    float mrow[2];
    #pragma unroll
    for (int m = 0; m < 2; ++m) {
        float q2 = 0.f;
        #pragma unroll
        for (int ks = 0; ks < 2; ++ks)
            #pragma unroll
            for (int i = 0; i < 8; ++i) {
                float qv = bf2f((u16)qf[m][ks][i]); q2 += qv * qv;
            }
        q2 += __shfl_xor(q2, 32, 64);
        mrow[m] = SCALE * sqrtf(q2) * maxk[bh];
    }

    fx16 acc[2][2];
    #pragma unroll
    for (int a1 = 0; a1 < 2; ++a1)
        #pragma unroll
        for (int a2 = 0; a2 < 2; ++a2)
            #pragma unroll
            for (int e = 0; e < 16; ++e) acc[a1][a2][e] = 0.f;
    float lsum[2] = {0.f, 0.f};

    fx16 z16;
    #pragma unroll
    for (int e = 0; e < 16; ++e) z16[e] = 0.f;

    // QK phase: keys [kt2 + w*32, +32) x all 64 q -> exp -> Pb[bsel]
    auto qk_phase = [&](bf8_t kf0, bf8_t kf1, int bsel) {
        #pragma unroll
        for (int m = 0; m < 2; ++m) {
            fx16 s = __builtin_amdgcn_mfma_f32_32x32x16_bf16(kf0, qf[m][0], z16, 0, 0, 0);
            s = __builtin_amdgcn_mfma_f32_32x32x16_bf16(kf1, qf[m][1], s, 0, 0, 0);
            char* wrow = (char*)&Pb[bsel][0][0] + (m * 32 + l31) * 256;
            float ls = 0.f;
            #pragma unroll
            for (int g = 0; g < 4; ++g) {
                float p0 = __expf(fmaf(s[4 * g + 0], SCALE, -mrow[m]));
                float p1 = __expf(fmaf(s[4 * g + 1], SCALE, -mrow[m]));
                float p2 = __expf(fmaf(s[4 * g + 2], SCALE, -mrow[m]));
                float p3 = __expf(fmaf(s[4 * g + 3], SCALE, -mrow[m]));
                ls += (p0 + p1) + (p2 + p3);
                ushort4 pk;
                pk.x = f2bf(p0); pk.y = f2bf(p1); pk.z = f2bf(p2); pk.w = f2bf(p3);
                // key col = w*32 + 8g + 4hi (+0..3) -> byte 64w+16g+8hi, XOR swizzle
                *(ushort4*)(wrow + ((w * 64 + 16 * g + 8 * hi) ^ sw)) = pk;
            }
            lsum[m] += ls;
        }
    };

    // prologue: QK for chunk 0
    {
        const u16* kp = kh + ((size_t)bh * 64 + w) * 1024 + l31 * 16 + hi * 8;
        bf8_t kf0 = *(const bf8_t*)kp;
        bf8_t kf1 = *(const bf8_t*)(kp + 512);
        qk_phase(kf0, kf1, 0);
    }

    int buf = 0;
    for (int c = 0; c < 16; ++c) {
        __syncthreads();
        const int kt = c << 7;
        bf8_t kf0, kf1;
        if (c < 15) {   // issue next chunk's K loads early (hide under PV)
            const u16* kp = kh + ((size_t)bh * 64 + ((kt + 128) >> 5) + w) * 1024
                            + l31 * 16 + hi * 8;
            kf0 = *(const bf8_t*)kp;
            kf1 = *(const bf8_t*)(kp + 512);
        }
        // PV(c): Pb[buf] x V[kt..kt+128)
        const char* pb = (const char*)&Pb[buf][0][0];
        const u16* vp = vhT + (((size_t)bh * 128 + (kt >> 4)) * 256 + w * 64 + l31) * 16
                        + hi * 8;
        #pragma unroll
        for (int ks = 0; ks < 8; ++ks) {
            bf8_t pa0 = *(const bf8_t*)(pb + l31 * 256        + ((ks * 32 + hi * 16) ^ sw));
            bf8_t pa1 = *(const bf8_t*)(pb + (32 + l31) * 256 + ((ks * 32 + hi * 16) ^ sw));
            bf8_t vb0 = *(const bf8_t*)(vp + ks * 4096);
            bf8_t vb1 = *(const bf8_t*)(vp + ks * 4096 + 512);
            __builtin_amdgcn_s_setprio(1);
            acc[0][0] = __builtin_amdgcn_mfma_f32_32x32x16_bf16(pa0, vb0, acc[0][0], 0, 0, 0);
            acc[0][1] = __builtin_amdgcn_mfma_f32_32x32x16_bf16(pa0, vb1, acc[0][1], 0, 0, 0);
            acc[1][0] = __builtin_amdgcn_mfma_f32_32x32x16_bf16(pa1, vb0, acc[1][0], 0, 0, 0);
            acc[1][1] = __builtin_amdgcn_mfma_f32_32x32x16_bf16(pa1, vb1, acc[1][1], 0, 0, 0);
            __builtin_amdgcn_s_setprio(0);
        }
        if (c < 15) qk_phase(kf0, kf1, buf ^ 1);
        buf ^= 1;
    }

    // cross-wave lsum reduction
    #pragma unroll
    for (int m = 0; m < 2; ++m) {
        lsum[m] += __shfl_xor(lsum[m], 32, 64);
        if (hi == 0) lds_l[w][m * 32 + l31] = lsum[m];
    }
    __syncthreads();
    if (t < 64) lds_t[t] = lds_l[0][t] + lds_l[1][t] + lds_l[2][t] + lds_l[3][t];
    __syncthreads();

    #pragma unroll
    for (int mt = 0; mt < 2; ++mt)
        #pragma unroll
        for (int g = 0; g < 4; ++g) {
            f4_t lv = *(const f4_t*)&lds_t[mt * 32 + 8 * g + 4 * hi];
            #pragma unroll
            for (int j = 0; j < 4; ++j) {
                float inv = 1.0f / lv[j];
                int q = mt * 32 + 8 * g + 4 * hi + j;
                size_t rowbase = ((size_t)(b * 2048 + n0 + q)) * 2048 + h * 256 + w * 64;
                #pragma unroll
                for (int nt = 0; nt < 2; ++nt)
                    ao[rowbase + nt * 32 + l31] = f2bf(acc[mt][nt][g * 4 + j] * inv);
            }
        }
}

extern "C" void kernel_launch(void* const* d_in, const int* in_sizes, int n_in,
                              void* d_out, int out_size, void* d_ws, size_t ws_size,
                              hipStream_t stream)
{
    u16* wsu = (u16*)d_ws;
    int* flag = (int*)d_ws;
    float* mk = (float*)(wsu + 64);              // 32 f32

    // workspace layout (u16 units), ~95.7 MB (known-safe)
    const size_t CVT0 = 128;
    const size_t Y0   = CVT0 + SEG_TOT;          // y bf16 [8192,256]
    const size_t QH0  = Y0  + 2097152;
    const size_t KH0  = QH0 + 2097152;           // K tiled [bh][64][2][32][16]
    const size_t VT0  = KH0 + 2097152;           // V tiled [bh][128][256][16]
    const size_t AO0  = VT0 + 16777216;          // ao bf16 [8192][2048]
    const size_t X20  = AO0 + 16777216;          // x2 f32 [8192,256]
    // hbb bf16 [8192,1024] aliases AO0 (ao dead after merge GEMM)

    u16* cvt = wsu + CVT0;
    u16* y   = wsu + Y0;
    u16* qh  = wsu + QH0;
    u16* kh  = wsu + KH0;
    u16* vhT = wsu + VT0;
    u16* ao  = wsu + AO0;
    float* x2 = (float*)(wsu + X20);
    u16* hbb  = wsu + AO0;

    const u16* xc   = cvt + SEG_X;
    const u16* ln1g = cvt + SEG_LN1G;
    const u16* ln1b = cvt + SEG_LN1B;
    const u16* Wqkv = cvt + SEG_WQKV;   // transposed [2560][256]
    const u16* bqkv = cvt + SEG_BQKV;
    const u16* Wm   = cvt + SEG_WM;     // transposed [256][2048]
    const u16* bm   = cvt + SEG_BM;
    const u16* ln2g = cvt + SEG_LN2G;
    const u16* ln2b = cvt + SEG_LN2B;
    const u16* W1   = cvt + SEG_W1;     // transposed [1024][256]
    const u16* b1   = cvt + SEG_B1;
    const u16* W2   = cvt + SEG_W2;     // transposed [256][1024]
    const u16* b2   = cvt + SEG_B2;

    sniff_k<<<1, 256, 0, stream>>>((const u16*)d_in[0], flag);
    conv_k<<<SEG_TOT / 256, 256, 0, stream>>>(
        d_in[0], d_in[1], d_in[2], d_in[3], d_in[4], d_in[5], d_in[6],
        d_in[7], d_in[8], d_in[9], d_in[10], d_in[11], d_in[12], flag, cvt);

    ln_k<true><<<ROWS / 4, 256, 0, stream>>>(xc, ln1g, ln1b, y);
    gemm_big<EP_QKV><<<dim3(2560 / 64, ROWS / 256), 256, 0, stream>>>(
        y, Wqkv, bqkv, nullptr, qh, kh, vhT, 2560, 256);
    maxk_k<<<32, 256, 0, stream>>>(kh, mk);
    attn_k<<<1024, 256, 0, stream>>>(qh, kh, vhT, mk, ao);
    gemm_mfma<EP_MERGE><<<dim3(256 / 64, ROWS / 128), 256, 0, stream>>>(
        ao, Wm, bm, xc, x2, 256, 2048);
    ln_k<false><<<ROWS / 4, 256, 0, stream>>>(x2, ln2g, ln2b, y);
    gemm_big<EP_GELU><<<dim3(1024 / 64, ROWS / 256), 256, 0, stream>>>(
        y, W1, b1, hbb, nullptr, nullptr, nullptr, 1024, 256);
    gemm_mfma<EP_FFN2><<<dim3(256 / 64, ROWS / 128), 256, 0, stream>>>(
        hbb, W2, b2, x2, d_out, 256, 1024);
}

// Round 4
// 349.254 us; speedup vs baseline: 1.2330x; 1.0861x over previous
//
#include <hip/hip_runtime.h>

typedef unsigned short u16;
typedef __attribute__((ext_vector_type(8))) short bf8_t;   // 8 bf16 (4 VGPR) MFMA A/B frag
typedef __attribute__((ext_vector_type(4))) float f4_t;    // MFMA C/D frag (16x16)
typedef __attribute__((ext_vector_type(16))) float fx16;   // MFMA C/D frag (32x32)

__device__ __forceinline__ float bf2f(u16 v) {
    union { unsigned u; float f; } c; c.u = ((unsigned)v) << 16; return c.f;
}
__device__ __forceinline__ u16 f2bf(float f) {  // RNE f32 -> bf16
    union { float f; unsigned u; } c; c.f = f;
    unsigned r = 0x7FFFu + ((c.u >> 16) & 1u);
    return (u16)((c.u + r) >> 16);
}

#define B_   4
#define N_   2048
#define INC  256
#define H_   8
#define ROWS 8192

// canonical (bf16) segment offsets within cvt, u16 units. Weights stored TRANSPOSED: Bt[n][k].
#define SEG_X     0
#define SEG_LN1G  2097152
#define SEG_LN1B  2097408
#define SEG_WQKV  2097664
#define SEG_BQKV  2753024
#define SEG_WM    2755584
#define SEG_BM    3279872
#define SEG_LN2G  3280128
#define SEG_LN2B  3280384
#define SEG_W1    3280640
#define SEG_B1    3542784
#define SEG_W2    3543808
#define SEG_B2    3805952
#define SEG_TOT   3806208

// ---------------- dtype sniffer ----------------
__global__ __launch_bounds__(256) void sniff_k(const u16* __restrict__ x, int* __restrict__ flag) {
    __shared__ int s;
    int t = threadIdx.x;
    if (t == 0) s = 0;
    __syncthreads();
    int bad = 0;
    for (int i = t; i < 8192; i += 256) {
        float v = bf2f(x[i]);
        if (!(fabsf(v) < 1e10f)) bad = 1;
    }
    if (bad) atomicOr(&s, 1);
    __syncthreads();
    if (t == 0) *flag = s;   // 1 => inputs fp32, 0 => bf16
}

// ---------------- canonicalize inputs to bf16; weights transposed ----------------
__global__ __launch_bounds__(256) void conv_k(
    const void* p0, const void* p1, const void* p2, const void* p3, const void* p4,
    const void* p5, const void* p6, const void* p7, const void* p8, const void* p9,
    const void* p10, const void* p11, const void* p12,
    const int* __restrict__ flag, u16* __restrict__ dst)
{
    int i = blockIdx.x * 256 + threadIdx.x;
    if (i >= SEG_TOT) return;
    const void* p; int j;
    if      (i < SEG_LN1G) { p = p0;  j = i; }
    else if (i < SEG_LN1B) { p = p1;  j = i - SEG_LN1G; }
    else if (i < SEG_WQKV) { p = p2;  j = i - SEG_LN1B; }
    else if (i < SEG_BQKV) { p = p3;  int ii = i - SEG_WQKV;          // WqkvT[n][k]: n<2560,k<256
                             int n = ii >> 8, k = ii & 255; j = k * 2560 + n; }
    else if (i < SEG_WM)   { p = p4;  j = i - SEG_BQKV; }
    else if (i < SEG_BM)   { p = p5;  int ii = i - SEG_WM;            // WmT[n][k]: n<256,k<2048
                             int n = ii >> 11, k = ii & 2047; j = k * 256 + n; }
    else if (i < SEG_LN2G) { p = p6;  j = i - SEG_BM; }
    else if (i < SEG_LN2B) { p = p7;  j = i - SEG_LN2G; }
    else if (i < SEG_W1)   { p = p8;  j = i - SEG_LN2B; }
    else if (i < SEG_B1)   { p = p9;  int ii = i - SEG_W1;            // W1T[n][k]: n<1024,k<256
                             int n = ii >> 8, k = ii & 255; j = k * 1024 + n; }
    else if (i < SEG_W2)   { p = p10; j = i - SEG_B1; }
    else if (i < SEG_B2)   { p = p11; int ii = i - SEG_W2;            // W2T[n][k]: n<256,k<1024
                             int n = ii >> 10, k = ii & 1023; j = k * 256 + n; }
    else                   { p = p12; j = i - SEG_B2; }
    dst[i] = (*flag) ? f2bf(((const float*)p)[j]) : ((const u16*)p)[j];
}

// ---------------- LayerNorm, one wave per row (no barriers), 4 rows/block ----------------
template<bool BF16IN>
__global__ __launch_bounds__(256) void ln_k(const void* __restrict__ xp,
        const u16* __restrict__ g, const u16* __restrict__ b, u16* __restrict__ y)
{
    int row  = blockIdx.x * 4 + (threadIdx.x >> 6);
    int lane = threadIdx.x & 63;
    int c0   = lane * 4;
    float v[4];
    if (BF16IN) {
        ushort4 u = *(const ushort4*)((const u16*)xp + (size_t)row * INC + c0);
        v[0] = bf2f(u.x); v[1] = bf2f(u.y); v[2] = bf2f(u.z); v[3] = bf2f(u.w);
    } else {
        float4 f = *(const float4*)((const float*)xp + (size_t)row * INC + c0);
        v[0] = f.x; v[1] = f.y; v[2] = f.z; v[3] = f.w;
    }
    float s = v[0] + v[1] + v[2] + v[3];
    float s2 = v[0]*v[0] + v[1]*v[1] + v[2]*v[2] + v[3]*v[3];
    #pragma unroll
    for (int d = 1; d < 64; d <<= 1) {
        s  += __shfl_xor(s,  d, 64);
        s2 += __shfl_xor(s2, d, 64);
    }
    float mean = s * (1.0f / INC);
    float var  = s2 * (1.0f / INC) - mean * mean;
    float inv  = rsqrtf(var + 1e-5f);
    ushort4 gv = *(const ushort4*)(g + c0);
    ushort4 bv = *(const ushort4*)(b + c0);
    ushort4 o;
    o.x = f2bf((v[0] - mean) * inv * bf2f(gv.x) + bf2f(bv.x));
    o.y = f2bf((v[1] - mean) * inv * bf2f(gv.y) + bf2f(bv.y));
    o.z = f2bf((v[2] - mean) * inv * bf2f(gv.z) + bf2f(bv.z));
    o.w = f2bf((v[3] - mean) * inv * bf2f(gv.w) + bf2f(bv.w));
    *(ushort4*)(y + (size_t)row * INC + c0) = o;
}

// ---------------- per-head max key L2-norm (K tiled layout [bh][kb][cb][key32][ch16]) ------
__global__ __launch_bounds__(256) void maxk_k(const u16* __restrict__ kh, float* __restrict__ mk) {
    int bh = blockIdx.x, t = threadIdx.x;
    float mx = 0.f;
    for (int n = t; n < 2048; n += 256) {
        const u16* kr = kh + ((size_t)bh * 64 + (n >> 5)) * 1024 + (n & 31) * 16;
        float s = 0.f;
        #pragma unroll
        for (int cb = 0; cb < 2; ++cb)
            #pragma unroll
            for (int c4 = 0; c4 < 4; ++c4) {
                ushort4 v = *(const ushort4*)(kr + cb * 512 + c4 * 4);
                float f0 = bf2f(v.x), f1 = bf2f(v.y), f2 = bf2f(v.z), f3 = bf2f(v.w);
                s += f0 * f0 + f1 * f1 + f2 * f2 + f3 * f3;
            }
        mx = fmaxf(mx, s);
    }
    #pragma unroll
    for (int d = 1; d < 64; d <<= 1) mx = fmaxf(mx, __shfl_xor(mx, d, 64));
    __shared__ float red[4];
    if ((t & 63) == 0) red[t >> 6] = mx;
    __syncthreads();
    if (t == 0) mk[bh] = sqrtf(fmaxf(fmaxf(red[0], red[1]), fmaxf(red[2], red[3])));
}

enum { EP_QKV = 0, EP_MERGE = 1, EP_GELU = 2, EP_FFN2 = 3 };

// ---------------- big-tile GEMM (QKV / GELU): wave 64x64, block 256x64, 2:1 MFMA:load ----
template<int MODE>
__global__ __launch_bounds__(256) void gemm_big(
    const u16* __restrict__ A, const u16* __restrict__ Bt,
    const u16* __restrict__ bias, void* __restrict__ outp,
    u16* __restrict__ qh, u16* __restrict__ kh, u16* __restrict__ vh,
    int N, int K)
{
    const int t = threadIdx.x;
    const int w = t >> 6, lane = t & 63;
    const int l15 = lane & 15, quad = lane >> 4;
    const int col0 = blockIdx.x * 64;
    const int row0 = blockIdx.y * 256;
    const int mrow = row0 + w * 64;

    const u16* Ap = A  + (size_t)(mrow + l15) * K + quad * 8;
    const u16* Bp = Bt + (size_t)(col0 + l15) * K + quad * 8;

    f4_t acc[4][4];
    #pragma unroll
    for (int mi = 0; mi < 4; ++mi)
        #pragma unroll
        for (int ni = 0; ni < 4; ++ni)
            acc[mi][ni] = (f4_t){0.f, 0.f, 0.f, 0.f};

    for (int k0 = 0; k0 < K; k0 += 32) {
        bf8_t a[4], bb[4];
        #pragma unroll
        for (int mi = 0; mi < 4; ++mi)
            a[mi] = *(const bf8_t*)(Ap + (size_t)mi * 16 * K + k0);
        #pragma unroll
        for (int ni = 0; ni < 4; ++ni)
            bb[ni] = *(const bf8_t*)(Bp + (size_t)ni * 16 * K + k0);
        #pragma unroll
        for (int ni = 0; ni < 4; ++ni)
            #pragma unroll
            for (int mi = 0; mi < 4; ++mi)
                acc[mi][ni] = __builtin_amdgcn_mfma_f32_16x16x32_bf16(
                    a[mi], bb[ni], acc[mi][ni], 0, 0, 0);
    }

    if (MODE == EP_QKV) {
        if (col0 >= 512) {
            // V: transpose 256 tokens x 64 chans through LDS -> vh tiled [bh][tok/16][vc256][tok%16]
            __shared__ u16 Ts[64][268];
            #pragma unroll
            for (int mi = 0; mi < 4; ++mi)
                #pragma unroll
                for (int ni = 0; ni < 4; ++ni) {
                    float bz = bf2f(bias[col0 + ni * 16 + l15]);
                    #pragma unroll
                    for (int r = 0; r < 4; ++r)
                        Ts[ni * 16 + l15][w * 64 + mi * 16 + quad * 4 + r] =
                            f2bf(acc[mi][ni][r] + bz);
                }
            __syncthreads();
            int vcg = col0 - 512;
            int hh  = vcg >> 8;
            int bb2 = row0 >> 11, nb = row0 & 2047;
            int bhh = bb2 * 8 + hh;
            int tok4 = t & 3, cl = (t >> 2) & 63;
            int vc = (vcg & 255) + cl;
            // each kb-iteration: 256 threads store one fully-contiguous 2KB tile
            #pragma unroll
            for (int kb = 0; kb < 16; ++kb) {
                u16* dp = vh + (((size_t)bhh * 128 + ((nb >> 4) + kb)) * 256 + vc) * 16 + tok4 * 4;
                *(ushort4*)dp = *(const ushort4*)&Ts[cl][kb * 16 + tok4 * 4];
            }
        } else {
            #pragma unroll
            for (int mi = 0; mi < 4; ++mi)
                #pragma unroll
                for (int r = 0; r < 4; ++r) {
                    int rg = mrow + mi * 16 + quad * 4 + r;
                    int bb2 = rg >> 11, n = rg & 2047;
                    #pragma unroll
                    for (int ni = 0; ni < 4; ++ni) {
                        int col = col0 + ni * 16 + l15;
                        float v = acc[mi][ni][r] + bf2f(bias[col]);
                        if (col < 256)
                            qh[(((size_t)(bb2 * 8 + (col >> 5))) * 2048 + n) * 32 + (col & 31)] = f2bf(v);
                        else {
                            // K tiled: [bh][n/32][ch/16][n%32][ch%16]
                            int c2 = col - 256;
                            int hd = c2 >> 5, ch = c2 & 31;
                            kh[(((size_t)(bb2 * 8 + hd) * 64 + (n >> 5)) * 2 + (ch >> 4)) * 512
                               + (n & 31) * 16 + (ch & 15)] = f2bf(v);
                        }
                    }
                }
        }
    } else {   // EP_GELU: exact gelu -> bf16 hidden
        float bz[4];
        #pragma unroll
        for (int ni = 0; ni < 4; ++ni) bz[ni] = bf2f(bias[col0 + ni * 16 + l15]);
        #pragma unroll
        for (int mi = 0; mi < 4; ++mi)
            #pragma unroll
            for (int r = 0; r < 4; ++r) {
                int rg = mrow + mi * 16 + quad * 4 + r;
                size_t base = (size_t)rg * N + col0 + l15;
                #pragma unroll
                for (int ni = 0; ni < 4; ++ni) {
                    float v = acc[mi][ni][r] + bz[ni];
                    v = 0.5f * v * (1.0f + erff(v * 0.70710678118654752f));
                    ((u16*)outp)[base + ni * 16] = f2bf(v);
                }
            }
    }
}

// ---------------- MFMA GEMM (MERGE / FFN2): block 128x64 ----------------
template<int MODE>
__global__ __launch_bounds__(256) void gemm_mfma(
    const u16* __restrict__ A, const u16* __restrict__ Bt,
    const u16* __restrict__ bias, const void* __restrict__ res,
    void* __restrict__ outp, int N, int K)
{
    const int t = threadIdx.x;
    const int w = t >> 6, lane = t & 63;
    const int l15 = lane & 15, quad = lane >> 4;
    const int col0 = blockIdx.x * 64;
    const int row0 = blockIdx.y * 128;
    const int mrow = row0 + w * 32;

    const u16* Ap = A  + (size_t)(mrow + l15) * K + quad * 8;
    const u16* Bp = Bt + (size_t)(col0 + l15) * K + quad * 8;

    f4_t acc[2][4];
    #pragma unroll
    for (int mi = 0; mi < 2; ++mi)
        #pragma unroll
        for (int ni = 0; ni < 4; ++ni)
            acc[mi][ni] = (f4_t){0.f, 0.f, 0.f, 0.f};

    for (int k0 = 0; k0 < K; k0 += 64) {
        bf8_t a[2][2], bb[4][2];
        #pragma unroll
        for (int kc = 0; kc < 2; ++kc) {
            #pragma unroll
            for (int mi = 0; mi < 2; ++mi)
                a[mi][kc] = *(const bf8_t*)(Ap + (size_t)mi * 16 * K + k0 + kc * 32);
            #pragma unroll
            for (int ni = 0; ni < 4; ++ni)
                bb[ni][kc] = *(const bf8_t*)(Bp + (size_t)ni * 16 * K + k0 + kc * 32);
        }
        #pragma unroll
        for (int kc = 0; kc < 2; ++kc)
            #pragma unroll
            for (int ni = 0; ni < 4; ++ni)
                #pragma unroll
                for (int mi = 0; mi < 2; ++mi)
                    acc[mi][ni] = __builtin_amdgcn_mfma_f32_16x16x32_bf16(
                        a[mi][kc], bb[ni][kc], acc[mi][ni], 0, 0, 0);
    }

    float bz[4];
    #pragma unroll
    for (int ni = 0; ni < 4; ++ni) bz[ni] = bf2f(bias[col0 + ni * 16 + l15]);
    #pragma unroll
    for (int mi = 0; mi < 2; ++mi)
        #pragma unroll
        for (int r = 0; r < 4; ++r) {
            int rg = mrow + mi * 16 + quad * 4 + r;
            size_t base = (size_t)rg * N + col0 + l15;
            if (MODE == EP_MERGE) {          // + bm + x (bf16) -> f32 x2
                const u16* R = (const u16*)res;
                #pragma unroll
                for (int ni = 0; ni < 4; ++ni)
                    ((float*)outp)[base + ni * 16] =
                        acc[mi][ni][r] + bz[ni] + bf2f(R[base + ni * 16]);
            } else {                          // EP_FFN2: + x2 (f32) -> fp32 d_out
                const float* R = (const float*)res;
                #pragma unroll
                for (int ni = 0; ni < 4; ++ni)
                    ((float*)outp)[base + ni * 16] =
                        acc[mi][ni][r] + bz[ni] + R[base + ni * 16];
            }
        }
}

// ---------------- MFMA flash attention, 32x32x16, software-pipelined ----------------
// A/B experiment vs R3: SAME pipeline schedule, but value path reverted byte-exactly
// to the R1-proven one (__expf(fmaf(s,SCALE,-mrow)) + manual-RNE f2bf + ushort4 store).
// R3 (exp2 builtin + v_cvt_pk_bf16_f32 asm) failed absmax; this isolates which half broke.
// NOTE: plain launch_bounds(256). Capping VGPR below the 64-reg accumulator spills (R12 lesson).
__global__ __launch_bounds__(256) void attn_k(
    const u16* __restrict__ qh, const u16* __restrict__ kh,
    const u16* __restrict__ vhT, const float* __restrict__ maxk,
    u16* __restrict__ ao)
{
    const int t = threadIdx.x;
    const int w = t >> 6, lane = t & 63;
    const int l31 = lane & 31, hi = lane >> 5;
    const int id = blockIdx.x;
    const int qt = (id >> 3) & 31;
    const int bh = (id >> 8) * 8 + (id & 7);   // id%8 = XCD affinity per (b,h)
    const int b  = bh >> 3, h = bh & 7;
    const int n0 = qt * 64;
    const float SCALE = 0.17677669529663687f;  // 1/sqrt(32)
    const int sw = (l31 & 7) << 4;             // LDS XOR swizzle (byte bits 4-6)

    __shared__ __align__(16) u16 Pb[2][64][128];  // [buf][q][key], stride 256B, XOR-swizzled
    __shared__ float lds_l[4][64];
    __shared__ float lds_t[64];

    // Q fragments: qf[m][ks] = Q[n0+m*32+l31][ks*16 + hi*8 .. +8]  (B operand of QK)
    bf8_t qf[2][2];
    #pragma unroll
    for (int m = 0; m < 2; ++m)
        #pragma unroll
        for (int ks = 0; ks < 2; ++ks)
            qf[m][ks] = *(const bf8_t*)(qh + ((size_t)bh * 2048 + n0 + m * 32 + l31) * 32
                                        + ks * 16 + hi * 8);

    float mrow[2];
    #pragma unroll
    for (int m = 0; m < 2; ++m) {
        float q2 = 0.f;
        #pragma unroll
        for (int ks = 0; ks < 2; ++ks)
            #pragma unroll
            for (int i = 0; i < 8; ++i) {
                float qv = bf2f((u16)qf[m][ks][i]); q2 += qv * qv;
            }
        q2 += __shfl_xor(q2, 32, 64);
        mrow[m] = SCALE * sqrtf(q2) * maxk[bh];
    }

    fx16 acc[2][2];
    #pragma unroll
    for (int a1 = 0; a1 < 2; ++a1)
        #pragma unroll
        for (int a2 = 0; a2 < 2; ++a2)
            #pragma unroll
            for (int e = 0; e < 16; ++e) acc[a1][a2][e] = 0.f;
    float lsum[2] = {0.f, 0.f};

    fx16 z16;
    #pragma unroll
    for (int e = 0; e < 16; ++e) z16[e] = 0.f;

    // exp + pack + P-write for one (m, g) group of a score tile (R1-proven value path)
    auto finish = [&](const fx16& s, int m, int g, char* base) {
        float p0 = __expf(fmaf(s[4 * g + 0], SCALE, -mrow[m]));
        float p1 = __expf(fmaf(s[4 * g + 1], SCALE, -mrow[m]));
        float p2 = __expf(fmaf(s[4 * g + 2], SCALE, -mrow[m]));
        float p3 = __expf(fmaf(s[4 * g + 3], SCALE, -mrow[m]));
        lsum[m] += (p0 + p1) + (p2 + p3);
        ushort4 pk;
        pk.x = f2bf(p0); pk.y = f2bf(p1); pk.z = f2bf(p2); pk.w = f2bf(p3);
        *(ushort4*)(base + (m * 32 + l31) * 256 + ((w * 64 + 16 * g + 8 * hi) ^ sw)) = pk;
    };

    // K frags for chunk c: 32 keys starting at c*128 + w*32, both 16-chan halves
    bf8_t kA0, kA1;
    auto ldK = [&](int c) {
        const u16* kp = kh + ((size_t)bh * 64 + c * 4 + w) * 1024 + l31 * 16 + hi * 8;
        kA0 = *(const bf8_t*)kp;
        kA1 = *(const bf8_t*)(kp + 512);
    };

    // prologue: chunk 0 scores -> Pb[0]; preload K(1)
    {
        ldK(0);
        fx16 sA = __builtin_amdgcn_mfma_f32_32x32x16_bf16(kA0, qf[0][0], z16, 0, 0, 0);
        sA = __builtin_amdgcn_mfma_f32_32x32x16_bf16(kA1, qf[0][1], sA, 0, 0, 0);
        fx16 sB = __builtin_amdgcn_mfma_f32_32x32x16_bf16(kA0, qf[1][0], z16, 0, 0, 0);
        sB = __builtin_amdgcn_mfma_f32_32x32x16_bf16(kA1, qf[1][1], sB, 0, 0, 0);
        ldK(1);
        char* base0 = (char*)&Pb[0][0][0];
        #pragma unroll
        for (int g = 0; g < 4; ++g) finish(sA, 0, g, base0);
        #pragma unroll
        for (int g = 0; g < 4; ++g) finish(sB, 1, g, base0);
    }

    // V pipeline: 1-deep register prefetch, continuous across chunk boundaries.
    // (at c=15, ks=7 the prefetch reads 8KB past this bh's V tile -- still inside
    //  the owned vhT/ao workspace region, value unused)
    const u16* vpb = vhT + (((size_t)bh * 128) * 256 + w * 64 + l31) * 16 + hi * 8;
    bf8_t vb0 = *(const bf8_t*)vpb;
    bf8_t vb1 = *(const bf8_t*)(vpb + 512);

    int buf = 0;
    for (int c = 0; c < 16; ++c, buf ^= 1) {
        __syncthreads();
        const bool qn = (c < 15);
        fx16 sA, sB;
        if (qn) {   // scores for chunk c+1, q-tile m=0 (kA holds K(c+1))
            sA = __builtin_amdgcn_mfma_f32_32x32x16_bf16(kA0, qf[0][0], z16, 0, 0, 0);
            sA = __builtin_amdgcn_mfma_f32_32x32x16_bf16(kA1, qf[0][1], sA, 0, 0, 0);
        }
        const char* pb = (const char*)&Pb[buf][0][0];
        char* wr = (char*)&Pb[buf ^ 1][0][0];
        const u16* vp = vpb + (size_t)c * 32768;
        #pragma unroll
        for (int ks = 0; ks < 8; ++ks) {
            bf8_t nv0 = *(const bf8_t*)(vp + (ks + 1) * 4096);
            bf8_t nv1 = *(const bf8_t*)(vp + (ks + 1) * 4096 + 512);
            bf8_t pa0 = *(const bf8_t*)(pb + l31 * 256        + ((ks * 32 + hi * 16) ^ sw));
            bf8_t pa1 = *(const bf8_t*)(pb + (32 + l31) * 256 + ((ks * 32 + hi * 16) ^ sw));
            __builtin_amdgcn_s_setprio(1);
            acc[0][0] = __builtin_amdgcn_mfma_f32_32x32x16_bf16(pa0, vb0, acc[0][0], 0, 0, 0);
            acc[0][1] = __builtin_amdgcn_mfma_f32_32x32x16_bf16(pa0, vb1, acc[0][1], 0, 0, 0);
            acc[1][0] = __builtin_amdgcn_mfma_f32_32x32x16_bf16(pa1, vb0, acc[1][0], 0, 0, 0);
            acc[1][1] = __builtin_amdgcn_mfma_f32_32x32x16_bf16(pa1, vb1, acc[1][1], 0, 0, 0);
            __builtin_amdgcn_s_setprio(0);
            if (qn) {
                if (ks < 4) {
                    finish(sA, 0, ks, wr);
                    if (ks == 3) {   // sA consumed: compute m=1 scores, then recycle kA
                        sB = __builtin_amdgcn_mfma_f32_32x32x16_bf16(kA0, qf[1][0], z16, 0, 0, 0);
                        sB = __builtin_amdgcn_mfma_f32_32x32x16_bf16(kA1, qf[1][1], sB, 0, 0, 0);
                        if (c < 14) ldK(c + 2);
                    }
                } else {
                    finish(sB, 1, ks - 4, wr);
                }
            }
            vb0 = nv0; vb1 = nv1;
        }
    }

    // cross-wave lsum reduction
    #pragma unroll
    for (int m = 0; m < 2; ++m) {
        lsum[m] += __shfl_xor(lsum[m], 32, 64);
        if (hi == 0) lds_l[w][m * 32 + l31] = lsum[m];
    }
    __syncthreads();
    if (t < 64) lds_t[t] = lds_l[0][t] + lds_l[1][t] + lds_l[2][t] + lds_l[3][t];
    __syncthreads();

    #pragma unroll
    for (int mt = 0; mt < 2; ++mt)
        #pragma unroll
        for (int g = 0; g < 4; ++g) {
            f4_t lv = *(const f4_t*)&lds_t[mt * 32 + 8 * g + 4 * hi];
            #pragma unroll
            for (int j = 0; j < 4; ++j) {
                float inv = 1.0f / lv[j];
                int q = mt * 32 + 8 * g + 4 * hi + j;
                size_t rowbase = ((size_t)(b * 2048 + n0 + q)) * 2048 + h * 256 + w * 64;
                #pragma unroll
                for (int nt = 0; nt < 2; ++nt)
                    ao[rowbase + nt * 32 + l31] = f2bf(acc[mt][nt][g * 4 + j] * inv);
            }
        }
}

extern "C" void kernel_launch(void* const* d_in, const int* in_sizes, int n_in,
                              void* d_out, int out_size, void* d_ws, size_t ws_size,
                              hipStream_t stream)
{
    u16* wsu = (u16*)d_ws;
    int* flag = (int*)d_ws;
    float* mk = (float*)(wsu + 64);              // 32 f32

    // workspace layout (u16 units), ~95.7 MB (known-safe)
    const size_t CVT0 = 128;
    const size_t Y0   = CVT0 + SEG_TOT;          // y bf16 [8192,256]
    const size_t QH0  = Y0  + 2097152;
    const size_t KH0  = QH0 + 2097152;           // K tiled [bh][64][2][32][16]
    const size_t VT0  = KH0 + 2097152;           // V tiled [bh][128][256][16]
    const size_t AO0  = VT0 + 16777216;          // ao bf16 [8192][2048]
    const size_t X20  = AO0 + 16777216;          // x2 f32 [8192,256]
    // hbb bf16 [8192,1024] aliases AO0 (ao dead after merge GEMM)

    u16* cvt = wsu + CVT0;
    u16* y   = wsu + Y0;
    u16* qh  = wsu + QH0;
    u16* kh  = wsu + KH0;
    u16* vhT = wsu + VT0;
    u16* ao  = wsu + AO0;
    float* x2 = (float*)(wsu + X20);
    u16* hbb  = wsu + AO0;

    const u16* xc   = cvt + SEG_X;
    const u16* ln1g = cvt + SEG_LN1G;
    const u16* ln1b = cvt + SEG_LN1B;
    const u16* Wqkv = cvt + SEG_WQKV;   // transposed [2560][256]
    const u16* bqkv = cvt + SEG_BQKV;
    const u16* Wm   = cvt + SEG_WM;     // transposed [256][2048]
    const u16* bm   = cvt + SEG_BM;
    const u16* ln2g = cvt + SEG_LN2G;
    const u16* ln2b = cvt + SEG_LN2B;
    const u16* W1   = cvt + SEG_W1;     // transposed [1024][256]
    const u16* b1   = cvt + SEG_B1;
    const u16* W2   = cvt + SEG_W2;     // transposed [256][1024]
    const u16* b2   = cvt + SEG_B2;

    sniff_k<<<1, 256, 0, stream>>>((const u16*)d_in[0], flag);
    conv_k<<<SEG_TOT / 256, 256, 0, stream>>>(
        d_in[0], d_in[1], d_in[2], d_in[3], d_in[4], d_in[5], d_in[6],
        d_in[7], d_in[8], d_in[9], d_in[10], d_in[11], d_in[12], flag, cvt);

    ln_k<true><<<ROWS / 4, 256, 0, stream>>>(xc, ln1g, ln1b, y);
    gemm_big<EP_QKV><<<dim3(2560 / 64, ROWS / 256), 256, 0, stream>>>(
        y, Wqkv, bqkv, nullptr, qh, kh, vhT, 2560, 256);
    maxk_k<<<32, 256, 0, stream>>>(kh, mk);
    attn_k<<<1024, 256, 0, stream>>>(qh, kh, vhT, mk, ao);
    gemm_mfma<EP_MERGE><<<dim3(256 / 64, ROWS / 128), 256, 0, stream>>>(
        ao, Wm, bm, xc, x2, 256, 2048);
    ln_k<false><<<ROWS / 4, 256, 0, stream>>>(x2, ln2g, ln2b, y);
    gemm_big<EP_GELU><<<dim3(1024 / 64, ROWS / 256), 256, 0, stream>>>(
        y, W1, b1, hbb, nullptr, nullptr, nullptr, 1024, 256);
    gemm_mfma<EP_FFN2><<<dim3(256 / 64, ROWS / 128), 256, 0, stream>>>(
        hbb, W2, b2, x2, d_out, 256, 1024);
}

// Round 5
// 337.736 us; speedup vs baseline: 1.2751x; 1.0341x over previous
//
#include <hip/hip_runtime.h>

typedef unsigned short u16;
typedef __attribute__((ext_vector_type(8))) short bf8_t;   // 8 bf16 (4 VGPR) MFMA A/B frag
typedef __attribute__((ext_vector_type(4))) float f4_t;    // MFMA C/D frag (16x16)
typedef __attribute__((ext_vector_type(16))) float fx16;   // MFMA C/D frag (32x32)

__device__ __forceinline__ float bf2f(u16 v) {
    union { unsigned u; float f; } c; c.u = ((unsigned)v) << 16; return c.f;
}
__device__ __forceinline__ u16 f2bf(float f) {  // RNE f32 -> bf16
    union { float f; unsigned u; } c; c.f = f;
    unsigned r = 0x7FFFu + ((c.u >> 16) & 1u);
    return (u16)((c.u + r) >> 16);
}

#define B_   4
#define N_   2048
#define INC  256
#define H_   8
#define ROWS 8192

// canonical (bf16) segment offsets within cvt, u16 units. Weights stored TRANSPOSED: Bt[n][k].
// All segment boundaries are 256-aligned -> every conv block lies in exactly one segment.
#define SEG_X     0
#define SEG_LN1G  2097152
#define SEG_LN1B  2097408
#define SEG_WQKV  2097664
#define SEG_BQKV  2753024
#define SEG_WM    2755584
#define SEG_BM    3279872
#define SEG_LN2G  3280128
#define SEG_LN2B  3280384
#define SEG_W1    3280640
#define SEG_B1    3542784
#define SEG_W2    3543808
#define SEG_B2    3805952
#define SEG_TOT   3806208

// ---------------- canonicalize inputs (self-sniffing) + fused LN1 for x rows ----------------
// Blocks 0..8191: one x row each (256 ch). Convert to bf16 xc AND write y = LN1(x) directly.
// Other blocks: segment conversion as before. Block 8192 also zeroes the head-norm slots.
__global__ __launch_bounds__(256) void conv_k(
    const void* p0, const void* p1, const void* p2, const void* p3, const void* p4,
    const void* p5, const void* p6, const void* p7, const void* p8, const void* p9,
    const void* p10, const void* p11, const void* p12,
    u16* __restrict__ dst, u16* __restrict__ y, int* __restrict__ mkz)
{
    const int t = threadIdx.x;
    const int blk = blockIdx.x;

    // self-sniff: sample x[0..1023] as u16; fp32 input's mantissa halfwords blow the bf16 range
    __shared__ int sflag;
    if (t == 0) sflag = 0;
    __syncthreads();
    int bad = 0;
    #pragma unroll
    for (int k2 = 0; k2 < 4; ++k2) {
        float v = bf2f(((const u16*)p0)[t * 4 + k2]);
        if (!(fabsf(v) < 1e10f)) bad = 1;
    }
    if (bad) atomicOr(&sflag, 1);
    __syncthreads();
    const int flag = sflag;   // 1 => inputs fp32, 0 => bf16

    if (blk == 8192 && t < 32) mkz[t] = 0;   // zero per-(b,h) max key norm^2

    const int i = blk * 256 + t;
    if (i >= SEG_TOT) return;

    if (i < SEG_LN1G) {       // x row: convert + fused LN1
        float v = flag ? ((const float*)p0)[i] : bf2f(((const u16*)p0)[i]);
        dst[i] = f2bf(v);
        float s = v, s2 = v * v;
        #pragma unroll
        for (int d = 1; d < 64; d <<= 1) {
            s  += __shfl_xor(s,  d, 64);
            s2 += __shfl_xor(s2, d, 64);
        }
        __shared__ float rs[8];
        int w = t >> 6;
        if ((t & 63) == 0) { rs[w] = s; rs[4 + w] = s2; }
        __syncthreads();
        s  = rs[0] + rs[1] + rs[2] + rs[3];
        s2 = rs[4] + rs[5] + rs[6] + rs[7];
        float mean = s * (1.0f / INC);
        float var  = s2 * (1.0f / INC) - mean * mean;
        float inv  = rsqrtf(var + 1e-5f);
        float g  = flag ? ((const float*)p1)[t] : bf2f(((const u16*)p1)[t]);
        float bb = flag ? ((const float*)p2)[t] : bf2f(((const u16*)p2)[t]);
        y[i] = f2bf((v - mean) * inv * g + bb);
        return;
    }

    const void* p; int j;
    if      (i < SEG_LN1B) { p = p1;  j = i - SEG_LN1G; }
    else if (i < SEG_WQKV) { p = p2;  j = i - SEG_LN1B; }
    else if (i < SEG_BQKV) { p = p3;  int ii = i - SEG_WQKV;          // WqkvT[n][k]: n<2560,k<256
                             int n = ii >> 8, k = ii & 255; j = k * 2560 + n; }
    else if (i < SEG_WM)   { p = p4;  j = i - SEG_BQKV; }
    else if (i < SEG_BM)   { p = p5;  int ii = i - SEG_WM;            // WmT[n][k]: n<256,k<2048
                             int n = ii >> 11, k = ii & 2047; j = k * 256 + n; }
    else if (i < SEG_LN2G) { p = p6;  j = i - SEG_BM; }
    else if (i < SEG_LN2B) { p = p7;  j = i - SEG_LN2G; }
    else if (i < SEG_W1)   { p = p8;  j = i - SEG_LN2B; }
    else if (i < SEG_B1)   { p = p9;  int ii = i - SEG_W1;            // W1T[n][k]: n<1024,k<256
                             int n = ii >> 8, k = ii & 255; j = k * 1024 + n; }
    else if (i < SEG_W2)   { p = p10; j = i - SEG_B1; }
    else if (i < SEG_B2)   { p = p11; int ii = i - SEG_W2;            // W2T[n][k]: n<256,k<1024
                             int n = ii >> 10, k = ii & 1023; j = k * 256 + n; }
    else                   { p = p12; j = i - SEG_B2; }
    dst[i] = flag ? f2bf(((const float*)p)[j]) : ((const u16*)p)[j];
}

// ---------------- LayerNorm (f32 input), one wave per row, 4 rows/block ----------------
template<bool BF16IN>
__global__ __launch_bounds__(256) void ln_k(const void* __restrict__ xp,
        const u16* __restrict__ g, const u16* __restrict__ b, u16* __restrict__ y)
{
    int row  = blockIdx.x * 4 + (threadIdx.x >> 6);
    int lane = threadIdx.x & 63;
    int c0   = lane * 4;
    float v[4];
    if (BF16IN) {
        ushort4 u = *(const ushort4*)((const u16*)xp + (size_t)row * INC + c0);
        v[0] = bf2f(u.x); v[1] = bf2f(u.y); v[2] = bf2f(u.z); v[3] = bf2f(u.w);
    } else {
        float4 f = *(const float4*)((const float*)xp + (size_t)row * INC + c0);
        v[0] = f.x; v[1] = f.y; v[2] = f.z; v[3] = f.w;
    }
    float s = v[0] + v[1] + v[2] + v[3];
    float s2 = v[0]*v[0] + v[1]*v[1] + v[2]*v[2] + v[3]*v[3];
    #pragma unroll
    for (int d = 1; d < 64; d <<= 1) {
        s  += __shfl_xor(s,  d, 64);
        s2 += __shfl_xor(s2, d, 64);
    }
    float mean = s * (1.0f / INC);
    float var  = s2 * (1.0f / INC) - mean * mean;
    float inv  = rsqrtf(var + 1e-5f);
    ushort4 gv = *(const ushort4*)(g + c0);
    ushort4 bv = *(const ushort4*)(b + c0);
    ushort4 o;
    o.x = f2bf((v[0] - mean) * inv * bf2f(gv.x) + bf2f(bv.x));
    o.y = f2bf((v[1] - mean) * inv * bf2f(gv.y) + bf2f(bv.y));
    o.z = f2bf((v[2] - mean) * inv * bf2f(gv.z) + bf2f(bv.z));
    o.w = f2bf((v[3] - mean) * inv * bf2f(gv.w) + bf2f(bv.w));
    *(ushort4*)(y + (size_t)row * INC + c0) = o;
}

enum { EP_QKV = 0, EP_MERGE = 1, EP_GELU = 2, EP_FFN2 = 3 };

// ---------------- big-tile GEMM (QKV / GELU): wave 64x64, block 256x64, 2:1 MFMA:load ----
// QKV K-epilogue also computes per-head max key L2-norm^2 via shuffle-reduce + atomicMax
// (f32 >= 0 so int-compare == float-compare), replacing the separate maxk kernel.
template<int MODE>
__global__ __launch_bounds__(256) void gemm_big(
    const u16* __restrict__ A, const u16* __restrict__ Bt,
    const u16* __restrict__ bias, void* __restrict__ outp,
    u16* __restrict__ qh, u16* __restrict__ kh, u16* __restrict__ vh,
    int* __restrict__ mkz, int N, int K)
{
    const int t = threadIdx.x;
    const int w = t >> 6, lane = t & 63;
    const int l15 = lane & 15, quad = lane >> 4;
    const int col0 = blockIdx.x * 64;
    const int row0 = blockIdx.y * 256;
    const int mrow = row0 + w * 64;

    const u16* Ap = A  + (size_t)(mrow + l15) * K + quad * 8;
    const u16* Bp = Bt + (size_t)(col0 + l15) * K + quad * 8;

    f4_t acc[4][4];
    #pragma unroll
    for (int mi = 0; mi < 4; ++mi)
        #pragma unroll
        for (int ni = 0; ni < 4; ++ni)
            acc[mi][ni] = (f4_t){0.f, 0.f, 0.f, 0.f};

    for (int k0 = 0; k0 < K; k0 += 32) {
        bf8_t a[4], bb[4];
        #pragma unroll
        for (int mi = 0; mi < 4; ++mi)
            a[mi] = *(const bf8_t*)(Ap + (size_t)mi * 16 * K + k0);
        #pragma unroll
        for (int ni = 0; ni < 4; ++ni)
            bb[ni] = *(const bf8_t*)(Bp + (size_t)ni * 16 * K + k0);
        #pragma unroll
        for (int ni = 0; ni < 4; ++ni)
            #pragma unroll
            for (int mi = 0; mi < 4; ++mi)
                acc[mi][ni] = __builtin_amdgcn_mfma_f32_16x16x32_bf16(
                    a[mi], bb[ni], acc[mi][ni], 0, 0, 0);
    }

    if (MODE == EP_QKV) {
        if (col0 >= 512) {
            // V: transpose 256 tokens x 64 chans through LDS -> vh tiled [bh][tok/16][vc256][tok%16]
            __shared__ u16 Ts[64][268];
            #pragma unroll
            for (int mi = 0; mi < 4; ++mi)
                #pragma unroll
                for (int ni = 0; ni < 4; ++ni) {
                    float bz = bf2f(bias[col0 + ni * 16 + l15]);
                    #pragma unroll
                    for (int r = 0; r < 4; ++r)
                        Ts[ni * 16 + l15][w * 64 + mi * 16 + quad * 4 + r] =
                            f2bf(acc[mi][ni][r] + bz);
                }
            __syncthreads();
            int vcg = col0 - 512;
            int hh  = vcg >> 8;
            int bb2 = row0 >> 11, nb = row0 & 2047;
            int bhh = bb2 * 8 + hh;
            int tok4 = t & 3, cl = (t >> 2) & 63;
            int vc = (vcg & 255) + cl;
            // each kb-iteration: 256 threads store one fully-contiguous 2KB tile
            #pragma unroll
            for (int kb = 0; kb < 16; ++kb) {
                u16* dp = vh + (((size_t)bhh * 128 + ((nb >> 4) + kb)) * 256 + vc) * 16 + tok4 * 4;
                *(ushort4*)dp = *(const ushort4*)&Ts[cl][kb * 16 + tok4 * 4];
            }
        } else if (col0 < 256) {   // Q cols
            #pragma unroll
            for (int mi = 0; mi < 4; ++mi)
                #pragma unroll
                for (int r = 0; r < 4; ++r) {
                    int rg = mrow + mi * 16 + quad * 4 + r;
                    int bb2 = rg >> 11, n = rg & 2047;
                    #pragma unroll
                    for (int ni = 0; ni < 4; ++ni) {
                        int col = col0 + ni * 16 + l15;
                        float v = acc[mi][ni][r] + bf2f(bias[col]);
                        qh[(((size_t)(bb2 * 8 + (col >> 5))) * 2048 + n) * 32 + (col & 31)] = f2bf(v);
                    }
                }
        } else {                   // K cols: store tiled + fused per-head max norm^2
            const int hA  = (col0 - 256) >> 5;       // block covers heads hA, hA+1
            const int bb2 = row0 >> 11;
            float mxA = 0.f, mxB = 0.f;
            #pragma unroll
            for (int mi = 0; mi < 4; ++mi)
                #pragma unroll
                for (int r = 0; r < 4; ++r) {
                    int rg = mrow + mi * 16 + quad * 4 + r;
                    int n = rg & 2047;
                    float vv[4];
                    #pragma unroll
                    for (int ni = 0; ni < 4; ++ni) {
                        int col = col0 + ni * 16 + l15;
                        float v = acc[mi][ni][r] + bf2f(bias[col]);
                        vv[ni] = v;
                        int c2 = col - 256;
                        int hd = c2 >> 5, ch = c2 & 31;
                        // K tiled: [bh][n/32][ch/16][n%32][ch%16]
                        kh[(((size_t)(bb2 * 8 + hd) * 64 + (n >> 5)) * 2 + (ch >> 4)) * 512
                           + (n & 31) * 16 + (ch & 15)] = f2bf(v);
                    }
                    float sA = vv[0] * vv[0] + vv[1] * vv[1];
                    float sB = vv[2] * vv[2] + vv[3] * vv[3];
                    #pragma unroll
                    for (int d = 1; d < 16; d <<= 1) {
                        sA += __shfl_xor(sA, d, 64);
                        sB += __shfl_xor(sB, d, 64);
                    }
                    mxA = fmaxf(mxA, sA);
                    mxB = fmaxf(mxB, sB);
                }
            if ((lane & 15) == 0) {
                atomicMax(mkz + bb2 * 8 + hA,     __float_as_int(mxA));
                atomicMax(mkz + bb2 * 8 + hA + 1, __float_as_int(mxB));
            }
        }
    } else {   // EP_GELU: exact gelu -> bf16 hidden
        float bz[4];
        #pragma unroll
        for (int ni = 0; ni < 4; ++ni) bz[ni] = bf2f(bias[col0 + ni * 16 + l15]);
        #pragma unroll
        for (int mi = 0; mi < 4; ++mi)
            #pragma unroll
            for (int r = 0; r < 4; ++r) {
                int rg = mrow + mi * 16 + quad * 4 + r;
                size_t base = (size_t)rg * N + col0 + l15;
                #pragma unroll
                for (int ni = 0; ni < 4; ++ni) {
                    float v = acc[mi][ni][r] + bz[ni];
                    v = 0.5f * v * (1.0f + erff(v * 0.70710678118654752f));
                    ((u16*)outp)[base + ni * 16] = f2bf(v);
                }
            }
    }
}

// ---------------- MFMA GEMM (MERGE / FFN2): block 128x64 ----------------
template<int MODE>
__global__ __launch_bounds__(256) void gemm_mfma(
    const u16* __restrict__ A, const u16* __restrict__ Bt,
    const u16* __restrict__ bias, const void* __restrict__ res,
    void* __restrict__ outp, int N, int K)
{
    const int t = threadIdx.x;
    const int w = t >> 6, lane = t & 63;
    const int l15 = lane & 15, quad = lane >> 4;
    const int col0 = blockIdx.x * 64;
    const int row0 = blockIdx.y * 128;
    const int mrow = row0 + w * 32;

    const u16* Ap = A  + (size_t)(mrow + l15) * K + quad * 8;
    const u16* Bp = Bt + (size_t)(col0 + l15) * K + quad * 8;

    f4_t acc[2][4];
    #pragma unroll
    for (int mi = 0; mi < 2; ++mi)
        #pragma unroll
        for (int ni = 0; ni < 4; ++ni)
            acc[mi][ni] = (f4_t){0.f, 0.f, 0.f, 0.f};

    for (int k0 = 0; k0 < K; k0 += 64) {
        bf8_t a[2][2], bb[4][2];
        #pragma unroll
        for (int kc = 0; kc < 2; ++kc) {
            #pragma unroll
            for (int mi = 0; mi < 2; ++mi)
                a[mi][kc] = *(const bf8_t*)(Ap + (size_t)mi * 16 * K + k0 + kc * 32);
            #pragma unroll
            for (int ni = 0; ni < 4; ++ni)
                bb[ni][kc] = *(const bf8_t*)(Bp + (size_t)ni * 16 * K + k0 + kc * 32);
        }
        #pragma unroll
        for (int kc = 0; kc < 2; ++kc)
            #pragma unroll
            for (int ni = 0; ni < 4; ++ni)
                #pragma unroll
                for (int mi = 0; mi < 2; ++mi)
                    acc[mi][ni] = __builtin_amdgcn_mfma_f32_16x16x32_bf16(
                        a[mi][kc], bb[ni][kc], acc[mi][ni], 0, 0, 0);
    }

    float bz[4];
    #pragma unroll
    for (int ni = 0; ni < 4; ++ni) bz[ni] = bf2f(bias[col0 + ni * 16 + l15]);
    #pragma unroll
    for (int mi = 0; mi < 2; ++mi)
        #pragma unroll
        for (int r = 0; r < 4; ++r) {
            int rg = mrow + mi * 16 + quad * 4 + r;
            size_t base = (size_t)rg * N + col0 + l15;
            if (MODE == EP_MERGE) {          // + bm + x (bf16) -> f32 x2
                const u16* R = (const u16*)res;
                #pragma unroll
                for (int ni = 0; ni < 4; ++ni)
                    ((float*)outp)[base + ni * 16] =
                        acc[mi][ni][r] + bz[ni] + bf2f(R[base + ni * 16]);
            } else {                          // EP_FFN2: + x2 (f32) -> fp32 d_out
                const float* R = (const float*)res;
                #pragma unroll
                for (int ni = 0; ni < 4; ++ni)
                    ((float*)outp)[base + ni * 16] =
                        acc[mi][ni][r] + bz[ni] + R[base + ni * 16];
            }
        }
}

// ---------------- MFMA flash attention, 32x32x16, software-pipelined (R4-proven) ----------
// mk2[bh] now holds max key-norm SQUARED (from QKV-fused atomics); bound = sqrt(q2*mk2).
// NOTE: plain launch_bounds(256). Capping VGPR below the 64-reg accumulator spills (R12 lesson).
__global__ __launch_bounds__(256) void attn_k(
    const u16* __restrict__ qh, const u16* __restrict__ kh,
    const u16* __restrict__ vhT, const float* __restrict__ mk2,
    u16* __restrict__ ao)
{
    const int t = threadIdx.x;
    const int w = t >> 6, lane = t & 63;
    const int l31 = lane & 31, hi = lane >> 5;
    const int id = blockIdx.x;
    const int qt = (id >> 3) & 31;
    const int bh = (id >> 8) * 8 + (id & 7);   // id%8 = XCD affinity per (b,h)
    const int b  = bh >> 3, h = bh & 7;
    const int n0 = qt * 64;
    const float SCALE = 0.17677669529663687f;  // 1/sqrt(32)
    const int sw = (l31 & 7) << 4;             // LDS XOR swizzle (byte bits 4-6)

    __shared__ __align__(16) u16 Pb[2][64][128];  // [buf][q][key], stride 256B, XOR-swizzled
    __shared__ float lds_l[4][64];
    __shared__ float lds_t[64];

    // Q fragments: qf[m][ks] = Q[n0+m*32+l31][ks*16 + hi*8 .. +8]  (B operand of QK)
    bf8_t qf[2][2];
    #pragma unroll
    for (int m = 0; m < 2; ++m)
        #pragma unroll
        for (int ks = 0; ks < 2; ++ks)
            qf[m][ks] = *(const bf8_t*)(qh + ((size_t)bh * 2048 + n0 + m * 32 + l31) * 32
                                        + ks * 16 + hi * 8);

    float mrow[2];
    #pragma unroll
    for (int m = 0; m < 2; ++m) {
        float q2 = 0.f;
        #pragma unroll
        for (int ks = 0; ks < 2; ++ks)
            #pragma unroll
            for (int i = 0; i < 8; ++i) {
                float qv = bf2f((u16)qf[m][ks][i]); q2 += qv * qv;
            }
        q2 += __shfl_xor(q2, 32, 64);
        mrow[m] = SCALE * sqrtf(q2 * mk2[bh]);
    }

    fx16 acc[2][2];
    #pragma unroll
    for (int a1 = 0; a1 < 2; ++a1)
        #pragma unroll
        for (int a2 = 0; a2 < 2; ++a2)
            #pragma unroll
            for (int e = 0; e < 16; ++e) acc[a1][a2][e] = 0.f;
    float lsum[2] = {0.f, 0.f};

    fx16 z16;
    #pragma unroll
    for (int e = 0; e < 16; ++e) z16[e] = 0.f;

    // exp + pack + P-write for one (m, g) group of a score tile (R1-proven value path)
    auto finish = [&](const fx16& s, int m, int g, char* base) {
        float p0 = __expf(fmaf(s[4 * g + 0], SCALE, -mrow[m]));
        float p1 = __expf(fmaf(s[4 * g + 1], SCALE, -mrow[m]));
        float p2 = __expf(fmaf(s[4 * g + 2], SCALE, -mrow[m]));
        float p3 = __expf(fmaf(s[4 * g + 3], SCALE, -mrow[m]));
        lsum[m] += (p0 + p1) + (p2 + p3);
        ushort4 pk;
        pk.x = f2bf(p0); pk.y = f2bf(p1); pk.z = f2bf(p2); pk.w = f2bf(p3);
        *(ushort4*)(base + (m * 32 + l31) * 256 + ((w * 64 + 16 * g + 8 * hi) ^ sw)) = pk;
    };

    // K frags for chunk c: 32 keys starting at c*128 + w*32, both 16-chan halves
    bf8_t kA0, kA1;
    auto ldK = [&](int c) {
        const u16* kp = kh + ((size_t)bh * 64 + c * 4 + w) * 1024 + l31 * 16 + hi * 8;
        kA0 = *(const bf8_t*)kp;
        kA1 = *(const bf8_t*)(kp + 512);
    };

    // prologue: chunk 0 scores -> Pb[0]; preload K(1)
    {
        ldK(0);
        fx16 sA = __builtin_amdgcn_mfma_f32_32x32x16_bf16(kA0, qf[0][0], z16, 0, 0, 0);
        sA = __builtin_amdgcn_mfma_f32_32x32x16_bf16(kA1, qf[0][1], sA, 0, 0, 0);
        fx16 sB = __builtin_amdgcn_mfma_f32_32x32x16_bf16(kA0, qf[1][0], z16, 0, 0, 0);
        sB = __builtin_amdgcn_mfma_f32_32x32x16_bf16(kA1, qf[1][1], sB, 0, 0, 0);
        ldK(1);
        char* base0 = (char*)&Pb[0][0][0];
        #pragma unroll
        for (int g = 0; g < 4; ++g) finish(sA, 0, g, base0);
        #pragma unroll
        for (int g = 0; g < 4; ++g) finish(sB, 1, g, base0);
    }

    // V pipeline: 1-deep register prefetch, continuous across chunk boundaries.
    // (at c=15, ks=7 the prefetch reads 8KB past this bh's V tile -- still inside
    //  the owned vhT/ao workspace region, value unused)
    const u16* vpb = vhT + (((size_t)bh * 128) * 256 + w * 64 + l31) * 16 + hi * 8;
    bf8_t vb0 = *(const bf8_t*)vpb;
    bf8_t vb1 = *(const bf8_t*)(vpb + 512);

    int buf = 0;
    for (int c = 0; c < 16; ++c, buf ^= 1) {
        __syncthreads();
        const bool qn = (c < 15);
        fx16 sA, sB;
        if (qn) {   // scores for chunk c+1, q-tile m=0 (kA holds K(c+1))
            sA = __builtin_amdgcn_mfma_f32_32x32x16_bf16(kA0, qf[0][0], z16, 0, 0, 0);
            sA = __builtin_amdgcn_mfma_f32_32x32x16_bf16(kA1, qf[0][1], sA, 0, 0, 0);
        }
        const char* pb = (const char*)&Pb[buf][0][0];
        char* wr = (char*)&Pb[buf ^ 1][0][0];
        const u16* vp = vpb + (size_t)c * 32768;
        #pragma unroll
        for (int ks = 0; ks < 8; ++ks) {
            bf8_t nv0 = *(const bf8_t*)(vp + (ks + 1) * 4096);
            bf8_t nv1 = *(const bf8_t*)(vp + (ks + 1) * 4096 + 512);
            bf8_t pa0 = *(const bf8_t*)(pb + l31 * 256        + ((ks * 32 + hi * 16) ^ sw));
            bf8_t pa1 = *(const bf8_t*)(pb + (32 + l31) * 256 + ((ks * 32 + hi * 16) ^ sw));
            __builtin_amdgcn_s_setprio(1);
            acc[0][0] = __builtin_amdgcn_mfma_f32_32x32x16_bf16(pa0, vb0, acc[0][0], 0, 0, 0);
            acc[0][1] = __builtin_amdgcn_mfma_f32_32x32x16_bf16(pa0, vb1, acc[0][1], 0, 0, 0);
            acc[1][0] = __builtin_amdgcn_mfma_f32_32x32x16_bf16(pa1, vb0, acc[1][0], 0, 0, 0);
            acc[1][1] = __builtin_amdgcn_mfma_f32_32x32x16_bf16(pa1, vb1, acc[1][1], 0, 0, 0);
            __builtin_amdgcn_s_setprio(0);
            if (qn) {
                if (ks < 4) {
                    finish(sA, 0, ks, wr);
                    if (ks == 3) {   // sA consumed: compute m=1 scores, then recycle kA
                        sB = __builtin_amdgcn_mfma_f32_32x32x16_bf16(kA0, qf[1][0], z16, 0, 0, 0);
                        sB = __builtin_amdgcn_mfma_f32_32x32x16_bf16(kA1, qf[1][1], sB, 0, 0, 0);
                        if (c < 14) ldK(c + 2);
                    }
                } else {
                    finish(sB, 1, ks - 4, wr);
                }
            }
            vb0 = nv0; vb1 = nv1;
        }
    }

    // cross-wave lsum reduction
    #pragma unroll
    for (int m = 0; m < 2; ++m) {
        lsum[m] += __shfl_xor(lsum[m], 32, 64);
        if (hi == 0) lds_l[w][m * 32 + l31] = lsum[m];
    }
    __syncthreads();
    if (t < 64) lds_t[t] = lds_l[0][t] + lds_l[1][t] + lds_l[2][t] + lds_l[3][t];
    __syncthreads();

    #pragma unroll
    for (int mt = 0; mt < 2; ++mt)
        #pragma unroll
        for (int g = 0; g < 4; ++g) {
            f4_t lv = *(const f4_t*)&lds_t[mt * 32 + 8 * g + 4 * hi];
            #pragma unroll
            for (int j = 0; j < 4; ++j) {
                float inv = 1.0f / lv[j];
                int q = mt * 32 + 8 * g + 4 * hi + j;
                size_t rowbase = ((size_t)(b * 2048 + n0 + q)) * 2048 + h * 256 + w * 64;
                #pragma unroll
                for (int nt = 0; nt < 2; ++nt)
                    ao[rowbase + nt * 32 + l31] = f2bf(acc[mt][nt][g * 4 + j] * inv);
            }
        }
}

extern "C" void kernel_launch(void* const* d_in, const int* in_sizes, int n_in,
                              void* d_out, int out_size, void* d_ws, size_t ws_size,
                              hipStream_t stream)
{
    u16* wsu = (u16*)d_ws;
    float* mk = (float*)(wsu + 64);              // 32 f32 (max key norm^2, int-atomics)

    // workspace layout (u16 units), ~95.7 MB (known-safe)
    const size_t CVT0 = 128;
    const size_t Y0   = CVT0 + SEG_TOT;          // y bf16 [8192,256]
    const size_t QH0  = Y0  + 2097152;
    const size_t KH0  = QH0 + 2097152;           // K tiled [bh][64][2][32][16]
    const size_t VT0  = KH0 + 2097152;           // V tiled [bh][128][256][16]
    const size_t AO0  = VT0 + 16777216;          // ao bf16 [8192][2048]
    const size_t X20  = AO0 + 16777216;          // x2 f32 [8192,256]
    // hbb bf16 [8192,1024] aliases AO0 (ao dead after merge GEMM)

    u16* cvt = wsu + CVT0;
    u16* y   = wsu + Y0;
    u16* qh  = wsu + QH0;
    u16* kh  = wsu + KH0;
    u16* vhT = wsu + VT0;
    u16* ao  = wsu + AO0;
    float* x2 = (float*)(wsu + X20);
    u16* hbb  = wsu + AO0;

    const u16* xc   = cvt + SEG_X;
    const u16* Wqkv = cvt + SEG_WQKV;   // transposed [2560][256]
    const u16* bqkv = cvt + SEG_BQKV;
    const u16* Wm   = cvt + SEG_WM;     // transposed [256][2048]
    const u16* bm   = cvt + SEG_BM;
    const u16* ln2g = cvt + SEG_LN2G;
    const u16* ln2b = cvt + SEG_LN2B;
    const u16* W1   = cvt + SEG_W1;     // transposed [1024][256]
    const u16* b1   = cvt + SEG_B1;
    const u16* W2   = cvt + SEG_W2;     // transposed [256][1024]
    const u16* b2   = cvt + SEG_B2;

    // fused: conv (self-sniff) + LN1 + mk zeroing
    conv_k<<<SEG_TOT / 256, 256, 0, stream>>>(
        d_in[0], d_in[1], d_in[2], d_in[3], d_in[4], d_in[5], d_in[6],
        d_in[7], d_in[8], d_in[9], d_in[10], d_in[11], d_in[12],
        cvt, y, (int*)mk);

    gemm_big<EP_QKV><<<dim3(2560 / 64, ROWS / 256), 256, 0, stream>>>(
        y, Wqkv, bqkv, nullptr, qh, kh, vhT, (int*)mk, 2560, 256);
    attn_k<<<1024, 256, 0, stream>>>(qh, kh, vhT, mk, ao);
    gemm_mfma<EP_MERGE><<<dim3(256 / 64, ROWS / 128), 256, 0, stream>>>(
        ao, Wm, bm, xc, x2, 256, 2048);
    ln_k<false><<<ROWS / 4, 256, 0, stream>>>(x2, ln2g, ln2b, y);
    gemm_big<EP_GELU><<<dim3(1024 / 64, ROWS / 256), 256, 0, stream>>>(
        y, W1, b1, hbb, nullptr, nullptr, nullptr, nullptr, 1024, 256);
    gemm_mfma<EP_FFN2><<<dim3(256 / 64, ROWS / 128), 256, 0, stream>>>(
        hbb, W2, b2, x2, d_out, 256, 1024);
}